// Round 3
// 88.013 us; speedup vs baseline: 1.0138x; 1.0138x over previous
//
#include <hip/hip_runtime.h>

#define BROWS 131072
#define CCOLS 64

__global__ __launch_bounds__(256) void mrl_kernel(
    const float* __restrict__ cand,   // [B, C] row-major
    const float* __restrict__ summ,   // [B]
    float* __restrict__ out)          // [1], pre-zeroed
{
    const int row = blockIdx.x * blockDim.x + threadIdx.x;

    // Load this thread's row: 16x float4 = 64 floats into registers.
    const float4* rp = reinterpret_cast<const float4*>(cand + (size_t)row * CCOLS);
    float x[CCOLS];
#pragma unroll
    for (int c4 = 0; c4 < CCOLS / 4; ++c4) {
        float4 v = rp[c4];
        x[4 * c4 + 0] = v.x;
        x[4 * c4 + 1] = v.y;
        x[4 * c4 + 2] = v.z;
        x[4 * c4 + 3] = v.w;
    }
    const float s = summ[row];

    // Summary term via max-trick:
    //   sum_c relu(x[c]-s) = sum_c max(x[c],s) - C*s
    float sa0 = 0.0f, sa1 = 0.0f;
#pragma unroll
    for (int c = 0; c < CCOLS; c += 2) {
        sa0 += fmaxf(x[c], s);
        sa1 += fmaxf(x[c + 1], s);
    }
    const float accS = (sa0 + sa1) - (float)CCOLS * s;
    float total = accS * (1.0f / ((float)BROWS * (float)CCOLS));

    // Transform x -> y so that x[j+i]-x[j]+0.01*i == y[j+i]-y[j].
#pragma unroll
    for (int c = 0; c < CCOLS; ++c)
        x[c] = fmaf(0.01f, (float)c, x[c]);

    // Pair terms grouped by distance i, using:
    //   relu(y[j+i]-y[j]) = max(y[j+i],y[j]) - y[j]
    //   sum_{j=0}^{m-1} relu = sum_j max(y[j+i],y[j]) - prefix[m],  m = C-i
    // Iterate i descending so prefix[m] is a running scalar (one add per i).
    float S = x[0];  // prefix sum of first m elements; m starts at 1 (i=63)
#pragma unroll
    for (int i = CCOLS - 1; i >= 1; --i) {
        const int m = CCOLS - i;
        float a0 = 0.0f, a1 = 0.0f;
#pragma unroll
        for (int j = 0; j + 1 < m; j += 2) {
            a0 += fmaxf(x[j + i], x[j]);
            a1 += fmaxf(x[j + 1 + i], x[j + 1]);
        }
        float acc = a0 + a1;
        if (m & 1)  // tail element j = m-1; note (m-1)+i == C-1
            acc += fmaxf(x[CCOLS - 1], x[m - 1]);
        total = fmaf(acc - S, 1.0f / ((float)BROWS * (float)(CCOLS - i)), total);
        if (m < CCOLS)
            S += x[m];  // prefix grows by one element for the next (smaller) i
    }

    // Wave64 reduction.
#pragma unroll
    for (int off = 32; off > 0; off >>= 1)
        total += __shfl_down(total, off, 64);

    __shared__ float ws[4];
    const int lane = threadIdx.x & 63;
    const int w = threadIdx.x >> 6;
    if (lane == 0) ws[w] = total;
    __syncthreads();
    if (threadIdx.x == 0) {
        float t = ws[0] + ws[1] + ws[2] + ws[3];
        atomicAdd(out, t);
    }
}

extern "C" void kernel_launch(void* const* d_in, const int* in_sizes, int n_in,
                              void* d_out, int out_size, void* d_ws, size_t ws_size,
                              hipStream_t stream) {
    const float* cand = (const float*)d_in[0];
    const float* summ = (const float*)d_in[1];
    float* out = (float*)d_out;

    // d_out is re-poisoned to 0xAA before every timed replay — zero it here.
    hipMemsetAsync(out, 0, sizeof(float), stream);

    const int threads = 256;
    const int blocks = BROWS / threads;  // 512
    mrl_kernel<<<blocks, threads, 0, stream>>>(cand, summ, out);
}